// Round 17
// baseline (198.544 us; speedup 1.0000x reference)
//
#include <hip/hip_runtime.h>

typedef short  short4v __attribute__((ext_vector_type(4)));
typedef short  short8v __attribute__((ext_vector_type(8)));
typedef __bf16 bf16x8  __attribute__((ext_vector_type(8)));
typedef float  f32x4   __attribute__((ext_vector_type(4)));
typedef float  float4v __attribute__((ext_vector_type(4)));

__device__ __forceinline__ short f2bf(float f) {
  unsigned u = __builtin_bit_cast(unsigned, f);
  u += 0x7fffu + ((u >> 16) & 1u);   // RNE
  return (short)(u >> 16);
}
__device__ __forceinline__ float bf2f(short h) {
  unsigned u = ((unsigned)(unsigned short)h) << 16;
  return __builtin_bit_cast(float, u);
}
__device__ __forceinline__ bf16x8 ld8(const short* p) {
  return __builtin_bit_cast(bf16x8, *reinterpret_cast<const short8v*>(p));
}

__constant__ const float kExpScale = 0.04508422f;   // log2(e)/32

// ---------- merged input prep: 2560 blocks (R16-proven) ----------
__global__ __launch_bounds__(256) void k_inprep(
    const float* __restrict__ x, short* __restrict__ xb,
    const float* __restrict__ i0, const float* __restrict__ i1,
    const float* __restrict__ i2, const float* __restrict__ i3,
    short* __restrict__ o0, short* __restrict__ o1,
    short* __restrict__ o2, short* __restrict__ o3) {
  const int bid = blockIdx.x;
  const int tid = threadIdx.x;
  if (bid < 2048) {
    const int i = bid * 256 + tid;
#pragma unroll
    for (int j = 0; j < 4; ++j) {
      const long g = (long)i + (long)j * 524288;
      float4v v = *reinterpret_cast<const float4v*>(x + g * 4);
      short4v o;
      o[0] = f2bf(v[0]); o[1] = f2bf(v[1]); o[2] = f2bf(v[2]); o[3] = f2bf(v[3]);
      *reinterpret_cast<short4v*>(xb + g * 4) = o;
    }
    return;
  }
  const int w = bid - 2048;
  const int z = w >> 7;
  const int rem = w & 127;
  const int c0 = (rem & 15) << 6;
  const int r0 = (rem >> 4) << 7;
  const float* in = z == 0 ? i0 : z == 1 ? i1 : z == 2 ? i2 : i3;
  short* out = z == 0 ? o0 : z == 1 ? o1 : z == 2 ? o2 : o3;
  const float sc = (z == 1) ? kExpScale : 1.0f;
  if (z == 3) {
#pragma unroll
    for (int j = 0; j < 8; ++j) {
      int idx = j * 256 + tid;
      int r = idx >> 4, c4 = (idx & 15) << 2;
      float4v v = *reinterpret_cast<const float4v*>(in + (long)(r0 + r) * 1024 + c0 + c4);
      short4v o;
      o[0] = f2bf(v[0]); o[1] = f2bf(v[1]); o[2] = f2bf(v[2]); o[3] = f2bf(v[3]);
      *reinterpret_cast<short4v*>(out + (long)(r0 + r) * 1024 + c0 + c4) = o;
    }
    return;
  }
  __shared__ float tile[128][65];
#pragma unroll
  for (int j = 0; j < 8; ++j) {
    int idx = j * 256 + tid;
    int r = idx >> 4, c4 = (idx & 15) << 2;
    float4v v = *reinterpret_cast<const float4v*>(in + (long)(r0 + r) * 1024 + c0 + c4);
    tile[r][c4 + 0] = v[0] * sc; tile[r][c4 + 1] = v[1] * sc;
    tile[r][c4 + 2] = v[2] * sc; tile[r][c4 + 3] = v[3] * sc;
  }
  __syncthreads();
#pragma unroll
  for (int j = 0; j < 8; ++j) {
    int idx = j * 256 + tid;
    int rO = idx >> 5, g4 = (idx & 31) << 2;
    short4v o;
    o[0] = f2bf(tile[g4 + 0][rO]); o[1] = f2bf(tile[g4 + 1][rO]);
    o[2] = f2bf(tile[g4 + 2][rO]); o[3] = f2bf(tile[g4 + 3][rO]);
    *reinterpret_cast<short4v*>(out + (long)(c0 + rO) * 1024 + r0 + g4) = o;
  }
}

// ---------- m97 core loop (4 waves, single-buffer, 128x128) ----------
__device__ __forceinline__ void gemm_loop(const short* __restrict__ Ab,
    const short* __restrict__ Bb, int K, int lda, int ldb, int bm, int bn,
    f32x4 (&acc)[4][4]) {
  __shared__ __align__(16) short lsA[128 * 64];
  __shared__ __align__(16) short lsB[128 * 64];
  const int tid = threadIdx.x;
  const int lane = tid & 63, wid = tid >> 6;
  const int wr = wid >> 1, wc = wid & 1;
  const int fr = lane & 15, fq = lane >> 4;
  for (int kt = 0; kt < K; kt += 64) {
    __syncthreads();
#pragma unroll
    for (int c = 0; c < 4; ++c) {
      const int idx = c * 256 + tid;
      const int row = idx >> 3, colh = (idx & 7) << 3;
      const short* ga = Ab + (long)(bm + row) * lda + kt + colh;
      const short* gb = Bb + (long)(bn + row) * ldb + kt + colh;
      __builtin_amdgcn_global_load_lds(
          (const __attribute__((address_space(1))) void*)ga,
          (__attribute__((address_space(3))) void*)&lsA[idx * 8], 16, 0, 0);
      __builtin_amdgcn_global_load_lds(
          (const __attribute__((address_space(1))) void*)gb,
          (__attribute__((address_space(3))) void*)&lsB[idx * 8], 16, 0, 0);
    }
    __syncthreads();
#pragma unroll
    for (int ks = 0; ks < 64; ks += 32) {
      bf16x8 a[4], b[4];
#pragma unroll
      for (int m = 0; m < 4; ++m)
        a[m] = ld8(&lsA[(wr * 64 + m * 16 + fr) * 64 + ks + fq * 8]);
#pragma unroll
      for (int n = 0; n < 4; ++n)
        b[n] = ld8(&lsB[(wc * 64 + n * 16 + fr) * 64 + ks + fq * 8]);
#pragma unroll
      for (int m = 0; m < 4; ++m)
#pragma unroll
        for (int n = 0; n < 4; ++n)
          acc[m][n] = __builtin_amdgcn_mfma_f32_16x16x32_bf16(a[m], b[n], acc[m][n], 0, 0, 0);
    }
  }
}

// ---------- 512-thr 128x256 single-buffer core (8 waves, 2M x 4N) ----------
__device__ __forceinline__ void gemm_loop_w(const short* __restrict__ Ab,
    const short* __restrict__ Bb, int K, int lda, int ldb, int bm, int bn,
    f32x4 (&acc)[4][4]) {
  __shared__ __align__(16) short lsA[128 * 64];
  __shared__ __align__(16) short lsB[256 * 64];
  const int tid = threadIdx.x;
  const int lane = tid & 63, wid = tid >> 6;
  const int wr = wid >> 2, wc = wid & 3;
  const int fr = lane & 15, fq = lane >> 4;
  for (int kt = 0; kt < K; kt += 64) {
    __syncthreads();
#pragma unroll
    for (int c = 0; c < 2; ++c) {
      const int idx = c * 512 + tid;
      const int row = idx >> 3, colh = (idx & 7) << 3;
      __builtin_amdgcn_global_load_lds(
          (const __attribute__((address_space(1))) void*)
              (Ab + (long)(bm + row) * lda + kt + colh),
          (__attribute__((address_space(3))) void*)&lsA[idx * 8], 16, 0, 0);
    }
#pragma unroll
    for (int c = 0; c < 4; ++c) {
      const int idx = c * 512 + tid;
      const int row = idx >> 3, colh = (idx & 7) << 3;
      __builtin_amdgcn_global_load_lds(
          (const __attribute__((address_space(1))) void*)
              (Bb + (long)(bn + row) * ldb + kt + colh),
          (__attribute__((address_space(3))) void*)&lsB[idx * 8], 16, 0, 0);
    }
    __syncthreads();
#pragma unroll
    for (int ks = 0; ks < 64; ks += 32) {
      bf16x8 a[4], b[4];
#pragma unroll
      for (int m = 0; m < 4; ++m)
        a[m] = ld8(&lsA[(wr * 64 + m * 16 + fr) * 64 + ks + fq * 8]);
#pragma unroll
      for (int n = 0; n < 4; ++n)
        b[n] = ld8(&lsB[(wc * 64 + n * 16 + fr) * 64 + ks + fq * 8]);
#pragma unroll
      for (int m = 0; m < 4; ++m)
#pragma unroll
        for (int n = 0; n < 4; ++n)
          acc[m][n] = __builtin_amdgcn_mfma_f32_16x16x32_bf16(a[m], b[n], acc[m][n], 0, 0, 0);
    }
  }
}

// ---------- prep2: grid (8,8,3) — tiny GEMMs + vector preps ----------
__global__ __launch_bounds__(256, 3) void k_prep2(
    const short* __restrict__ wkT, const short* __restrict__ wqT,
    const short* __restrict__ wob, const short* __restrict__ wvT,
    const float* __restrict__ bq, const float* __restrict__ Wo,
    const float* __restrict__ bv,
    short* __restrict__ mt, short* __restrict__ wv2,
    float* __restrict__ bvec, float* __restrict__ bvp) {
  const int tid = threadIdx.x;
  const int lane = tid & 63, wid = tid >> 6;
  if (blockIdx.z == 2) {
    const int r0 = (blockIdx.y * 8 + blockIdx.x) * 16;
#pragma unroll
    for (int rr = 0; rr < 4; ++rr) {
      const int row = r0 + wid * 4 + rr;
      {
        const short* xr = wkT + (long)row * 1024 + lane * 16;
        short8v a0 = *reinterpret_cast<const short8v*>(xr);
        short8v a1 = *reinterpret_cast<const short8v*>(xr + 8);
        float s = 0.f;
#pragma unroll
        for (int j = 0; j < 8; ++j) s += bf2f(a0[j]) * bq[lane * 16 + j];
#pragma unroll
        for (int j = 0; j < 8; ++j) s += bf2f(a1[j]) * bq[lane * 16 + 8 + j];
#pragma unroll
        for (int off = 32; off; off >>= 1) s += __shfl_xor(s, off);
        if (lane == 0) bvec[row] = s * kExpScale;
      }
      {
        float s = 0.f;
#pragma unroll
        for (int j = 0; j < 16; ++j)
          s += Wo[(long)row * 1024 + j * 64 + lane] * bv[j * 64 + lane];
#pragma unroll
        for (int off = 32; off; off >>= 1) s += __shfl_xor(s, off);
        if (lane == 0) bvp[row] = s;
      }
    }
    return;
  }
  const short* A = blockIdx.z == 0 ? wkT : wob;
  const short* B = blockIdx.z == 0 ? wqT : wvT;
  short* C = blockIdx.z == 0 ? mt : wv2;
  const int bm = blockIdx.x * 128, bn = blockIdx.y * 128;
  f32x4 acc[4][4] = {};
  gemm_loop(A, B, 1024, 1024, 1024, bm, bn, acc);
  const int wr = wid >> 1, wc = wid & 1;
  const int fr = lane & 15, fq = lane >> 4;
#pragma unroll
  for (int n = 0; n < 4; ++n) {
    const int col = bn + wc * 64 + n * 16 + fr;
#pragma unroll
    for (int m = 0; m < 4; ++m) {
      const int row0 = bm + wr * 64 + m * 16 + fq * 4;
#pragma unroll
      for (int i = 0; i < 4; ++i)
        C[(long)(row0 + i) * 1024 + col] = f2bf(acc[m][n][i]);
    }
  }
}

// ---------- fused TV: grid (64,9) ----------
// y<8: block (bm=x*128, j=y): stages xb[bm] ONCE + mt[j] + wv2[j] (3x16KB LDS),
//      computes T[bm][j] = xb*mt^T AND vTp[j][bm] = wv2*xb^T (32 MFMA/K-tile).
// y==8: w8 rowdots, 64 blocks x 128 rows.
__global__ __launch_bounds__(256, 3) void k_tvf(
    const short* __restrict__ xb, const short* __restrict__ mt,
    const short* __restrict__ wv2, const float* __restrict__ bvp,
    const float* __restrict__ bvec, short* __restrict__ T,
    short* __restrict__ vTp, float* __restrict__ w8) {
  const int tid = threadIdx.x;
  const int lane = tid & 63, wid = tid >> 6;
  if (blockIdx.y == 8) {
    const int rbase = blockIdx.x * 128 + wid * 32;
#pragma unroll 4
    for (int rr = 0; rr < 32; ++rr) {
      const int row = rbase + rr;
      const short* xr = xb + (long)row * 1024 + lane * 16;
      short8v a0 = *reinterpret_cast<const short8v*>(xr);
      short8v a1 = *reinterpret_cast<const short8v*>(xr + 8);
      float s = 0.f;
#pragma unroll
      for (int j = 0; j < 8; ++j) s += bf2f(a0[j]) * bvec[lane * 16 + j];
#pragma unroll
      for (int j = 0; j < 8; ++j) s += bf2f(a1[j]) * bvec[lane * 16 + 8 + j];
#pragma unroll
      for (int off = 32; off; off >>= 1) s += __shfl_xor(s, off);
      if (lane == 0) w8[row] = s;
    }
    return;
  }
  __shared__ __align__(16) short lsX[8192];
  __shared__ __align__(16) short lsM[8192];
  __shared__ __align__(16) short lsW[8192];
  const int wr = wid >> 1, wc = wid & 1;
  const int fr = lane & 15, fq = lane >> 4;
  const int bm = blockIdx.x * 128;
  const int jb = blockIdx.y * 128;
  const short* Xb = xb + (long)bm * 1024;
  const short* Mb = mt + (long)jb * 1024;
  const short* Wb = wv2 + (long)jb * 1024;

  f32x4 accT[4][4] = {}, accV[4][4] = {};

  for (int kt = 0; kt < 1024; kt += 64) {
    __syncthreads();
#pragma unroll
    for (int c = 0; c < 4; ++c) {
      const int idx = c * 256 + tid;
      const int row = idx >> 3, colh = (idx & 7) << 3;
      const long off = (long)row * 1024 + kt + colh;
      __builtin_amdgcn_global_load_lds(
          (const __attribute__((address_space(1))) void*)(Xb + off),
          (__attribute__((address_space(3))) void*)&lsX[idx * 8], 16, 0, 0);
      __builtin_amdgcn_global_load_lds(
          (const __attribute__((address_space(1))) void*)(Mb + off),
          (__attribute__((address_space(3))) void*)&lsM[idx * 8], 16, 0, 0);
      __builtin_amdgcn_global_load_lds(
          (const __attribute__((address_space(1))) void*)(Wb + off),
          (__attribute__((address_space(3))) void*)&lsW[idx * 8], 16, 0, 0);
    }
    __syncthreads();
#pragma unroll
    for (int ks = 0; ks < 64; ks += 32) {
      bf16x8 xa[4], xn[4], mb[4], wa[4];
#pragma unroll
      for (int m = 0; m < 4; ++m)
        xa[m] = ld8(&lsX[(wr * 64 + m * 16 + fr) * 64 + ks + fq * 8]);
#pragma unroll
      for (int n = 0; n < 4; ++n)
        xn[n] = ld8(&lsX[(wc * 64 + n * 16 + fr) * 64 + ks + fq * 8]);
#pragma unroll
      for (int n = 0; n < 4; ++n)
        mb[n] = ld8(&lsM[(wc * 64 + n * 16 + fr) * 64 + ks + fq * 8]);
#pragma unroll
      for (int m = 0; m < 4; ++m)
        wa[m] = ld8(&lsW[(wr * 64 + m * 16 + fr) * 64 + ks + fq * 8]);
#pragma unroll
      for (int m = 0; m < 4; ++m)
#pragma unroll
        for (int n = 0; n < 4; ++n) {
          accT[m][n] = __builtin_amdgcn_mfma_f32_16x16x32_bf16(xa[m], mb[n], accT[m][n], 0, 0, 0);
          accV[m][n] = __builtin_amdgcn_mfma_f32_16x16x32_bf16(wa[m], xn[n], accV[m][n], 0, 0, 0);
        }
    }
  }

#pragma unroll
  for (int n = 0; n < 4; ++n) {
    const int coln = wc * 64 + n * 16 + fr;
#pragma unroll
    for (int m = 0; m < 4; ++m) {
      const int rowm = wr * 64 + m * 16 + fq * 4;
#pragma unroll
      for (int i = 0; i < 4; ++i) {
        // T[bm + rowm + i][jb + coln]
        T[(long)(bm + rowm + i) * 1024 + jb + coln] = f2bf(accT[m][n][i]);
        // vTp[jb + rowm + i][bm + coln] + bvp row-bias
        vTp[(long)(jb + rowm + i) * 8192 + bm + coln] =
            f2bf(accV[m][n][i] + bvp[jb + rowm + i]);
      }
    }
  }
}

// ---------- scores: 128x256 single-buffer, 512 thr (R14-proven) ----------
__global__ __launch_bounds__(512, 2) void k_scores(
    const short* __restrict__ A, const short* __restrict__ B,
    const float* __restrict__ b0p, float* __restrict__ b1p,
    short* __restrict__ C0,
    int K, long sA, long sB, long sC, int ldC) {
  const int tid = threadIdx.x;
  const int lane = tid & 63, wid = tid >> 6;
  const int wr = wid >> 2, wc = wid & 3;
  const int fr = lane & 15, fq = lane >> 4;
  const int bm = blockIdx.x * 128, bn = blockIdx.y * 256;
  const int bz = blockIdx.z;

  f32x4 acc[4][4] = {};
  gemm_loop_w(A + (long)bz * sA, B + (long)bz * sB, K, K, K, bm, bn, acc);

  short* O = C0 + (long)bz * sC;
  float wv[4];
#pragma unroll
  for (int n = 0; n < 4; ++n)
    wv[n] = b0p[(long)bz * 2048 + bn + wc * 64 + n * 16 + fr];
#pragma unroll
  for (int m = 0; m < 4; ++m) {
#pragma unroll
    for (int i = 0; i < 4; ++i) {
      const int row = bm + wr * 64 + m * 16 + fq * 4 + i;
      float rs = 0.f;
#pragma unroll
      for (int n = 0; n < 4; ++n) {
        float e = exp2f(acc[m][n][i] + wv[n]);
        O[(long)row * ldC + bn + wc * 64 + n * 16 + fr] = f2bf(e);
        rs += e;
      }
      rs += __shfl_xor(rs, 1); rs += __shfl_xor(rs, 2);
      rs += __shfl_xor(rs, 4); rs += __shfl_xor(rs, 8);
      if (fr == 0)
        b1p[((long)bz * 2048 + row) * 32 + blockIdx.y * 4 + wc] = rs;
    }
  }
}

// ---------- PV: 256-thr 128x128 single-buffer (R12-proven), MODE 4 ----------
__global__ __launch_bounds__(256, 3) void k_pv(
    const short* __restrict__ A, const short* __restrict__ B,
    const float* __restrict__ b0p, float* __restrict__ b1p,
    float* __restrict__ C0,
    int K, int lda, int ldb, long sA, long sB, long sC, int ldC) {
  __shared__ float invL[128];
  const int tid = threadIdx.x;
  const int lane = tid & 63, wid = tid >> 6;
  const int wr = wid >> 1, wc = wid & 1;
  const int fr = lane & 15, fq = lane >> 4;
  const int bm = blockIdx.x * 128, bn = blockIdx.y * 128;
  const int bz = blockIdx.z;

  {
    const int row = tid >> 1, half = tid & 1;
    const float* pr = b1p + ((long)bz * 2048 + bm + row) * 32 + half * 16;
    float s = 0.f;
#pragma unroll
    for (int j = 0; j < 4; ++j) {
      float4v v = *reinterpret_cast<const float4v*>(pr + j * 4);
      s += v[0] + v[1] + v[2] + v[3];
    }
    s += __shfl_xor(s, 1);
    if (half == 0) invL[row] = 1.0f / s;
  }

  f32x4 acc[4][4] = {};
  gemm_loop(A + (long)bz * sA, B + (long)bz * sB, K, lda, ldb, bm, bn, acc);

#pragma unroll
  for (int n = 0; n < 4; ++n) {
    const int coll = wc * 64 + n * 16 + fr;
#pragma unroll
    for (int m = 0; m < 4; ++m) {
      const int rl0 = wr * 64 + m * 16 + fq * 4;
#pragma unroll
      for (int i = 0; i < 4; ++i) {
        const long row = bm + rl0 + i, col = bn + coll;
        float* O = C0 + (long)bz * sC;
        O[row * ldC + col] = acc[m][n][i] * invL[rl0 + i] + b0p[col];
      }
    }
  }
}

// ---------- launcher ----------
extern "C" void kernel_launch(void* const* d_in, const int* in_sizes, int n_in,
                              void* d_out, int out_size, void* d_ws, size_t ws_size,
                              hipStream_t stream) {
  const float* x  = (const float*)d_in[0];
  const float* Wq = (const float*)d_in[1];
  const float* bq = (const float*)d_in[2];
  const float* Wk = (const float*)d_in[3];
  // bk: provably no effect (softmax row-shift invariance) — unused.
  const float* Wv = (const float*)d_in[5];
  const float* bv = (const float*)d_in[6];
  const float* Wo = (const float*)d_in[7];
  const float* bo = (const float*)d_in[8];

  char* ws = (char*)d_ws;
  short* xb   = (short*)ws; ws += 8192L * 1024 * 2;     // x bf16
  short* wkT  = (short*)ws; ws += 1024L * 1024 * 2;     // Wk^T bf16
  short* wob  = (short*)ws; ws += 1024L * 1024 * 2;     // Wo bf16
  short* wqT  = (short*)ws; ws += 1024L * 1024 * 2;     // c*Wq^T bf16
  short* wvT  = (short*)ws; ws += 1024L * 1024 * 2;     // Wv^T bf16
  short* mt   = (short*)ws; ws += 1024L * 1024 * 2;     // Mt = Wk^T*(cWq)
  short* wv2  = (short*)ws; ws += 1024L * 1024 * 2;     // Wv'' = Wo*Wv
  short* T    = (short*)ws; ws += 8192L * 1024 * 2;     // T = x*Mt^T (pre-scaled)
  short* vTp  = (short*)ws; ws += 1024L * 8192 * 2;     // V'^T [e][b*2048+s]
  short* Sc   = (short*)ws; ws += 4L * 2048 * 2048 * 2; // exp-scores
  float* psum = (float*)ws; ws += 4L * 2048 * 32 * 4;   // row partial sums
  float* w8   = (float*)ws; ws += 8192L * 4;            // w' = c*x*(Wk^T bq)
  float* bvec = (float*)ws; ws += 1024L * 4;            // c * Wk^T bq
  float* bvp  = (float*)ws; ws += 1024L * 4;            // bv' = Wo * bv

  dim3 b256(256), b512(512);
  k_inprep<<<2560, b256, 0, stream>>>(
      x, xb, Wk, Wq, Wv, Wo, wkT, wqT, wvT, wob);
  k_prep2<<<dim3(8, 8, 3), b256, 0, stream>>>(
      wkT, wqT, wob, wvT, bq, Wo, bv, mt, wv2, bvec, bvp);
  // fused T + V'^T (shared xb staging) + w8 rowdots: grid (64,9)
  k_tvf<<<dim3(64, 9, 1), b256, 0, stream>>>(
      xb, mt, wv2, bvp, bvec, T, vTp, w8);
  // exp-scores: 128x256 single-buf, 512 blocks
  k_scores<<<dim3(16, 8, 4), b512, 0, stream>>>(
      T, xb, w8, psum, Sc,
      1024, 2048L * 1024, 2048L * 1024, 2048L * 2048, 2048);
  // out = (P_unnorm * V') / L + bo ; 128x128 single-buf, 512 blocks
  k_pv<<<dim3(16, 8, 4), b256, 0, stream>>>(
      Sc, vTp, bo, psum, (float*)d_out,
      2048, 2048, 8192, 2048L * 2048, 2048, 2048L * 1024, 1024);
}

// Round 18
// 187.117 us; speedup vs baseline: 1.0611x; 1.0611x over previous
//
#include <hip/hip_runtime.h>

typedef short  short4v __attribute__((ext_vector_type(4)));
typedef short  short8v __attribute__((ext_vector_type(8)));
typedef __bf16 bf16x8  __attribute__((ext_vector_type(8)));
typedef float  f32x4   __attribute__((ext_vector_type(4)));
typedef float  float4v __attribute__((ext_vector_type(4)));

__device__ __forceinline__ short f2bf(float f) {
  unsigned u = __builtin_bit_cast(unsigned, f);
  u += 0x7fffu + ((u >> 16) & 1u);   // RNE
  return (short)(u >> 16);
}
__device__ __forceinline__ float bf2f(short h) {
  unsigned u = ((unsigned)(unsigned short)h) << 16;
  return __builtin_bit_cast(float, u);
}
__device__ __forceinline__ bf16x8 ld8(const short* p) {
  return __builtin_bit_cast(bf16x8, *reinterpret_cast<const short8v*>(p));
}

__constant__ const float kExpScale = 0.04508422f;   // log2(e)/32

// ---------- merged input prep: 2560 blocks (R16-proven) ----------
__global__ __launch_bounds__(256) void k_inprep(
    const float* __restrict__ x, short* __restrict__ xb,
    const float* __restrict__ i0, const float* __restrict__ i1,
    const float* __restrict__ i2, const float* __restrict__ i3,
    short* __restrict__ o0, short* __restrict__ o1,
    short* __restrict__ o2, short* __restrict__ o3) {
  const int bid = blockIdx.x;
  const int tid = threadIdx.x;
  if (bid < 2048) {
    const int i = bid * 256 + tid;
#pragma unroll
    for (int j = 0; j < 4; ++j) {
      const long g = (long)i + (long)j * 524288;
      float4v v = *reinterpret_cast<const float4v*>(x + g * 4);
      short4v o;
      o[0] = f2bf(v[0]); o[1] = f2bf(v[1]); o[2] = f2bf(v[2]); o[3] = f2bf(v[3]);
      *reinterpret_cast<short4v*>(xb + g * 4) = o;
    }
    return;
  }
  const int w = bid - 2048;
  const int z = w >> 7;
  const int rem = w & 127;
  const int c0 = (rem & 15) << 6;
  const int r0 = (rem >> 4) << 7;
  const float* in = z == 0 ? i0 : z == 1 ? i1 : z == 2 ? i2 : i3;
  short* out = z == 0 ? o0 : z == 1 ? o1 : z == 2 ? o2 : o3;
  const float sc = (z == 1) ? kExpScale : 1.0f;
  if (z == 3) {
#pragma unroll
    for (int j = 0; j < 8; ++j) {
      int idx = j * 256 + tid;
      int r = idx >> 4, c4 = (idx & 15) << 2;
      float4v v = *reinterpret_cast<const float4v*>(in + (long)(r0 + r) * 1024 + c0 + c4);
      short4v o;
      o[0] = f2bf(v[0]); o[1] = f2bf(v[1]); o[2] = f2bf(v[2]); o[3] = f2bf(v[3]);
      *reinterpret_cast<short4v*>(out + (long)(r0 + r) * 1024 + c0 + c4) = o;
    }
    return;
  }
  __shared__ float tile[128][65];
#pragma unroll
  for (int j = 0; j < 8; ++j) {
    int idx = j * 256 + tid;
    int r = idx >> 4, c4 = (idx & 15) << 2;
    float4v v = *reinterpret_cast<const float4v*>(in + (long)(r0 + r) * 1024 + c0 + c4);
    tile[r][c4 + 0] = v[0] * sc; tile[r][c4 + 1] = v[1] * sc;
    tile[r][c4 + 2] = v[2] * sc; tile[r][c4 + 3] = v[3] * sc;
  }
  __syncthreads();
#pragma unroll
  for (int j = 0; j < 8; ++j) {
    int idx = j * 256 + tid;
    int rO = idx >> 5, g4 = (idx & 31) << 2;
    short4v o;
    o[0] = f2bf(tile[g4 + 0][rO]); o[1] = f2bf(tile[g4 + 1][rO]);
    o[2] = f2bf(tile[g4 + 2][rO]); o[3] = f2bf(tile[g4 + 3][rO]);
    *reinterpret_cast<short4v*>(out + (long)(c0 + rO) * 1024 + r0 + g4) = o;
  }
}

// ---------- m97 core loop (4 waves, single-buffer, 128x128) ----------
__device__ __forceinline__ void gemm_loop(const short* __restrict__ Ab,
    const short* __restrict__ Bb, int K, int lda, int ldb, int bm, int bn,
    f32x4 (&acc)[4][4]) {
  __shared__ __align__(16) short lsA[128 * 64];
  __shared__ __align__(16) short lsB[128 * 64];
  const int tid = threadIdx.x;
  const int lane = tid & 63, wid = tid >> 6;
  const int wr = wid >> 1, wc = wid & 1;
  const int fr = lane & 15, fq = lane >> 4;
  for (int kt = 0; kt < K; kt += 64) {
    __syncthreads();
#pragma unroll
    for (int c = 0; c < 4; ++c) {
      const int idx = c * 256 + tid;
      const int row = idx >> 3, colh = (idx & 7) << 3;
      const short* ga = Ab + (long)(bm + row) * lda + kt + colh;
      const short* gb = Bb + (long)(bn + row) * ldb + kt + colh;
      __builtin_amdgcn_global_load_lds(
          (const __attribute__((address_space(1))) void*)ga,
          (__attribute__((address_space(3))) void*)&lsA[idx * 8], 16, 0, 0);
      __builtin_amdgcn_global_load_lds(
          (const __attribute__((address_space(1))) void*)gb,
          (__attribute__((address_space(3))) void*)&lsB[idx * 8], 16, 0, 0);
    }
    __syncthreads();
#pragma unroll
    for (int ks = 0; ks < 64; ks += 32) {
      bf16x8 a[4], b[4];
#pragma unroll
      for (int m = 0; m < 4; ++m)
        a[m] = ld8(&lsA[(wr * 64 + m * 16 + fr) * 64 + ks + fq * 8]);
#pragma unroll
      for (int n = 0; n < 4; ++n)
        b[n] = ld8(&lsB[(wc * 64 + n * 16 + fr) * 64 + ks + fq * 8]);
#pragma unroll
      for (int m = 0; m < 4; ++m)
#pragma unroll
        for (int n = 0; n < 4; ++n)
          acc[m][n] = __builtin_amdgcn_mfma_f32_16x16x32_bf16(a[m], b[n], acc[m][n], 0, 0, 0);
    }
  }
}

// ---------- 512-thr 128x256 single-buffer core (8 waves, 2M x 4N) ----------
__device__ __forceinline__ void gemm_loop_w(const short* __restrict__ Ab,
    const short* __restrict__ Bb, int K, int lda, int ldb, int bm, int bn,
    f32x4 (&acc)[4][4]) {
  __shared__ __align__(16) short lsA[128 * 64];
  __shared__ __align__(16) short lsB[256 * 64];
  const int tid = threadIdx.x;
  const int lane = tid & 63, wid = tid >> 6;
  const int wr = wid >> 2, wc = wid & 3;
  const int fr = lane & 15, fq = lane >> 4;
  for (int kt = 0; kt < K; kt += 64) {
    __syncthreads();
#pragma unroll
    for (int c = 0; c < 2; ++c) {
      const int idx = c * 512 + tid;
      const int row = idx >> 3, colh = (idx & 7) << 3;
      __builtin_amdgcn_global_load_lds(
          (const __attribute__((address_space(1))) void*)
              (Ab + (long)(bm + row) * lda + kt + colh),
          (__attribute__((address_space(3))) void*)&lsA[idx * 8], 16, 0, 0);
    }
#pragma unroll
    for (int c = 0; c < 4; ++c) {
      const int idx = c * 512 + tid;
      const int row = idx >> 3, colh = (idx & 7) << 3;
      __builtin_amdgcn_global_load_lds(
          (const __attribute__((address_space(1))) void*)
              (Bb + (long)(bn + row) * ldb + kt + colh),
          (__attribute__((address_space(3))) void*)&lsB[idx * 8], 16, 0, 0);
    }
    __syncthreads();
#pragma unroll
    for (int ks = 0; ks < 64; ks += 32) {
      bf16x8 a[4], b[4];
#pragma unroll
      for (int m = 0; m < 4; ++m)
        a[m] = ld8(&lsA[(wr * 64 + m * 16 + fr) * 64 + ks + fq * 8]);
#pragma unroll
      for (int n = 0; n < 4; ++n)
        b[n] = ld8(&lsB[(wc * 64 + n * 16 + fr) * 64 + ks + fq * 8]);
#pragma unroll
      for (int m = 0; m < 4; ++m)
#pragma unroll
        for (int n = 0; n < 4; ++n)
          acc[m][n] = __builtin_amdgcn_mfma_f32_16x16x32_bf16(a[m], b[n], acc[m][n], 0, 0, 0);
    }
  }
}

// ---------- prep2: grid (8,8,3) — tiny GEMMs + vector preps ----------
__global__ __launch_bounds__(256, 3) void k_prep2(
    const short* __restrict__ wkT, const short* __restrict__ wqT,
    const short* __restrict__ wob, const short* __restrict__ wvT,
    const float* __restrict__ bq, const float* __restrict__ Wo,
    const float* __restrict__ bv,
    short* __restrict__ mt, short* __restrict__ wv2,
    float* __restrict__ bvec, float* __restrict__ bvp) {
  const int tid = threadIdx.x;
  const int lane = tid & 63, wid = tid >> 6;
  if (blockIdx.z == 2) {
    const int r0 = (blockIdx.y * 8 + blockIdx.x) * 16;
#pragma unroll
    for (int rr = 0; rr < 4; ++rr) {
      const int row = r0 + wid * 4 + rr;
      {
        const short* xr = wkT + (long)row * 1024 + lane * 16;
        short8v a0 = *reinterpret_cast<const short8v*>(xr);
        short8v a1 = *reinterpret_cast<const short8v*>(xr + 8);
        float s = 0.f;
#pragma unroll
        for (int j = 0; j < 8; ++j) s += bf2f(a0[j]) * bq[lane * 16 + j];
#pragma unroll
        for (int j = 0; j < 8; ++j) s += bf2f(a1[j]) * bq[lane * 16 + 8 + j];
#pragma unroll
        for (int off = 32; off; off >>= 1) s += __shfl_xor(s, off);
        if (lane == 0) bvec[row] = s * kExpScale;
      }
      {
        float s = 0.f;
#pragma unroll
        for (int j = 0; j < 16; ++j)
          s += Wo[(long)row * 1024 + j * 64 + lane] * bv[j * 64 + lane];
#pragma unroll
        for (int off = 32; off; off >>= 1) s += __shfl_xor(s, off);
        if (lane == 0) bvp[row] = s;
      }
    }
    return;
  }
  const short* A = blockIdx.z == 0 ? wkT : wob;
  const short* B = blockIdx.z == 0 ? wqT : wvT;
  short* C = blockIdx.z == 0 ? mt : wv2;
  const int bm = blockIdx.x * 128, bn = blockIdx.y * 128;
  f32x4 acc[4][4] = {};
  gemm_loop(A, B, 1024, 1024, 1024, bm, bn, acc);
  const int wr = wid >> 1, wc = wid & 1;
  const int fr = lane & 15, fq = lane >> 4;
#pragma unroll
  for (int n = 0; n < 4; ++n) {
    const int col = bn + wc * 64 + n * 16 + fr;
#pragma unroll
    for (int m = 0; m < 4; ++m) {
      const int row0 = bm + wr * 64 + m * 16 + fq * 4;
#pragma unroll
      for (int i = 0; i < 4; ++i)
        C[(long)(row0 + i) * 1024 + col] = f2bf(acc[m][n][i]);
    }
  }
}

// ---------- merged mid-stage launch, grid (64,8,3) — R14-proven ----------
__global__ __launch_bounds__(256, 3) void k_gemmTV(
    const short* __restrict__ xb, const short* __restrict__ mt,
    const short* __restrict__ wv2, const float* __restrict__ bvp,
    const float* __restrict__ bvec, short* __restrict__ T,
    short* __restrict__ vTp, float* __restrict__ w8) {
  const int tid = threadIdx.x;
  const int lane = tid & 63, wid = tid >> 6;
  if (blockIdx.z == 2) {
    const int rbase = (blockIdx.x * 8 + blockIdx.y) * 16;
#pragma unroll
    for (int rr = 0; rr < 4; ++rr) {
      const int row = rbase + wid * 4 + rr;
      const short* xr = xb + (long)row * 1024 + lane * 16;
      short8v a0 = *reinterpret_cast<const short8v*>(xr);
      short8v a1 = *reinterpret_cast<const short8v*>(xr + 8);
      float s = 0.f;
#pragma unroll
      for (int j = 0; j < 8; ++j) s += bf2f(a0[j]) * bvec[lane * 16 + j];
#pragma unroll
      for (int j = 0; j < 8; ++j) s += bf2f(a1[j]) * bvec[lane * 16 + 8 + j];
#pragma unroll
      for (int off = 32; off; off >>= 1) s += __shfl_xor(s, off);
      if (lane == 0) w8[row] = s;
    }
    return;
  }
  const short *A, *B; const float* bias; short* C; int ldC, bm, bn;
  if (blockIdx.z == 0) {
    A = xb; B = mt; bias = nullptr; C = T; ldC = 1024;
    bm = blockIdx.x * 128; bn = blockIdx.y * 128;
  } else {
    A = wv2; B = xb; bias = bvp; C = vTp; ldC = 8192;
    bm = blockIdx.y * 128; bn = blockIdx.x * 128;
  }
  f32x4 acc[4][4] = {};
  gemm_loop(A, B, 1024, 1024, 1024, bm, bn, acc);
  const int wr = wid >> 1, wc = wid & 1;
  const int fr = lane & 15, fq = lane >> 4;
#pragma unroll
  for (int n = 0; n < 4; ++n) {
    const int col = bn + wc * 64 + n * 16 + fr;
#pragma unroll
    for (int m = 0; m < 4; ++m) {
      const int row0 = bm + wr * 64 + m * 16 + fq * 4;
#pragma unroll
      for (int i = 0; i < 4; ++i) {
        const float bvr = bias ? bias[row0 + i] : 0.f;
        C[(long)(row0 + i) * ldC + col] = f2bf(acc[m][n][i] + bvr);
      }
    }
  }
}

// ---------- scores: 128x256 single-buffer, 512 thr (R14-proven) ----------
__global__ __launch_bounds__(512, 2) void k_scores(
    const short* __restrict__ A, const short* __restrict__ B,
    const float* __restrict__ b0p, float* __restrict__ b1p,
    short* __restrict__ C0,
    int K, long sA, long sB, long sC, int ldC) {
  const int tid = threadIdx.x;
  const int lane = tid & 63, wid = tid >> 6;
  const int wr = wid >> 2, wc = wid & 3;
  const int fr = lane & 15, fq = lane >> 4;
  const int bm = blockIdx.x * 128, bn = blockIdx.y * 256;
  const int bz = blockIdx.z;

  f32x4 acc[4][4] = {};
  gemm_loop_w(A + (long)bz * sA, B + (long)bz * sB, K, K, K, bm, bn, acc);

  short* O = C0 + (long)bz * sC;
  float wv[4];
#pragma unroll
  for (int n = 0; n < 4; ++n)
    wv[n] = b0p[(long)bz * 2048 + bn + wc * 64 + n * 16 + fr];
#pragma unroll
  for (int m = 0; m < 4; ++m) {
#pragma unroll
    for (int i = 0; i < 4; ++i) {
      const int row = bm + wr * 64 + m * 16 + fq * 4 + i;
      float rs = 0.f;
#pragma unroll
      for (int n = 0; n < 4; ++n) {
        float e = exp2f(acc[m][n][i] + wv[n]);
        O[(long)row * ldC + bn + wc * 64 + n * 16 + fr] = f2bf(e);
        rs += e;
      }
      rs += __shfl_xor(rs, 1); rs += __shfl_xor(rs, 2);
      rs += __shfl_xor(rs, 4); rs += __shfl_xor(rs, 8);
      if (fr == 0)
        b1p[((long)bz * 2048 + row) * 32 + blockIdx.y * 4 + wc] = rs;
    }
  }
}

// ---------- PV: 256-thr 128x128 single-buffer (R12-proven), MODE 4 ----------
__global__ __launch_bounds__(256, 3) void k_pv(
    const short* __restrict__ A, const short* __restrict__ B,
    const float* __restrict__ b0p, float* __restrict__ b1p,
    float* __restrict__ C0,
    int K, int lda, int ldb, long sA, long sB, long sC, int ldC) {
  __shared__ float invL[128];
  const int tid = threadIdx.x;
  const int lane = tid & 63, wid = tid >> 6;
  const int wr = wid >> 1, wc = wid & 1;
  const int fr = lane & 15, fq = lane >> 4;
  const int bm = blockIdx.x * 128, bn = blockIdx.y * 128;
  const int bz = blockIdx.z;

  {
    const int row = tid >> 1, half = tid & 1;
    const float* pr = b1p + ((long)bz * 2048 + bm + row) * 32 + half * 16;
    float s = 0.f;
#pragma unroll
    for (int j = 0; j < 4; ++j) {
      float4v v = *reinterpret_cast<const float4v*>(pr + j * 4);
      s += v[0] + v[1] + v[2] + v[3];
    }
    s += __shfl_xor(s, 1);
    if (half == 0) invL[row] = 1.0f / s;
  }

  f32x4 acc[4][4] = {};
  gemm_loop(A + (long)bz * sA, B + (long)bz * sB, K, lda, ldb, bm, bn, acc);

#pragma unroll
  for (int n = 0; n < 4; ++n) {
    const int coll = wc * 64 + n * 16 + fr;
#pragma unroll
    for (int m = 0; m < 4; ++m) {
      const int rl0 = wr * 64 + m * 16 + fq * 4;
#pragma unroll
      for (int i = 0; i < 4; ++i) {
        const long row = bm + rl0 + i, col = bn + coll;
        float* O = C0 + (long)bz * sC;
        O[row * ldC + col] = acc[m][n][i] * invL[rl0 + i] + b0p[col];
      }
    }
  }
}

// ---------- launcher ----------
extern "C" void kernel_launch(void* const* d_in, const int* in_sizes, int n_in,
                              void* d_out, int out_size, void* d_ws, size_t ws_size,
                              hipStream_t stream) {
  const float* x  = (const float*)d_in[0];
  const float* Wq = (const float*)d_in[1];
  const float* bq = (const float*)d_in[2];
  const float* Wk = (const float*)d_in[3];
  // bk: provably no effect (softmax row-shift invariance) — unused.
  const float* Wv = (const float*)d_in[5];
  const float* bv = (const float*)d_in[6];
  const float* Wo = (const float*)d_in[7];
  const float* bo = (const float*)d_in[8];

  char* ws = (char*)d_ws;
  short* xb   = (short*)ws; ws += 8192L * 1024 * 2;     // x bf16
  short* wkT  = (short*)ws; ws += 1024L * 1024 * 2;     // Wk^T bf16
  short* wob  = (short*)ws; ws += 1024L * 1024 * 2;     // Wo bf16
  short* wqT  = (short*)ws; ws += 1024L * 1024 * 2;     // c*Wq^T bf16
  short* wvT  = (short*)ws; ws += 1024L * 1024 * 2;     // Wv^T bf16
  short* mt   = (short*)ws; ws += 1024L * 1024 * 2;     // Mt = Wk^T*(cWq)
  short* wv2  = (short*)ws; ws += 1024L * 1024 * 2;     // Wv'' = Wo*Wv
  short* T    = (short*)ws; ws += 8192L * 1024 * 2;     // T = x*Mt^T (pre-scaled)
  short* vTp  = (short*)ws; ws += 1024L * 8192 * 2;     // V'^T [e][b*2048+s]
  short* Sc   = (short*)ws; ws += 4L * 2048 * 2048 * 2; // exp-scores
  float* psum = (float*)ws; ws += 4L * 2048 * 32 * 4;   // row partial sums
  float* w8   = (float*)ws; ws += 8192L * 4;            // w' = c*x*(Wk^T bq)
  float* bvec = (float*)ws; ws += 1024L * 4;            // c * Wk^T bq
  float* bvp  = (float*)ws; ws += 1024L * 4;            // bv' = Wo * bv

  dim3 b256(256), b512(512);
  // merged input prep: x convert (2048 blocks) + weight prep (512 blocks)
  k_inprep<<<2560, b256, 0, stream>>>(
      x, xb, Wk, Wq, Wv, Wo, wkT, wqT, wvT, wob);
  k_prep2<<<dim3(8, 8, 3), b256, 0, stream>>>(
      wkT, wqT, wob, wvT, bq, Wo, bv, mt, wv2, bvec, bvp);
  // T (z=0), V'^T (z=1), w8 (z=2) — R14 config: 1536 blocks, 3-res, 2.0 rounds
  k_gemmTV<<<dim3(64, 8, 3), b256, 0, stream>>>(
      xb, mt, wv2, bvp, bvec, T, vTp, w8);
  // exp-scores: 128x256 single-buf, 512 blocks = 2-res, 1.0 round
  k_scores<<<dim3(16, 8, 4), b512, 0, stream>>>(
      T, xb, w8, psum, Sc,
      1024, 2048L * 1024, 2048L * 1024, 2048L * 2048, 2048);
  // out = (P_unnorm * V') / L + bo ; 128x128 single-buf, 512 blocks, 3-res
  k_pv<<<dim3(16, 8, 4), b256, 0, stream>>>(
      Sc, vTp, bo, psum, (float*)d_out,
      2048, 2048, 8192, 2048L * 2048, 2048, 2048L * 1024, 1024);
}